// Round 5
// baseline (259.500 us; speedup 1.0000x reference)
//
#include <hip/hip_runtime.h>
#include <hip/hip_bf16.h>

typedef __hip_bfloat16 bf16;
typedef __attribute__((ext_vector_type(8))) short bf16x8;
typedef __attribute__((ext_vector_type(4))) float f32x4;

// Problem constants: B=64, n=m=14, E=512, D1=1024, heads=8
constexpr int NB    = 64;
constexpr int EE    = 512;
constexpr int DD1   = 1024;
constexpr int RPOS  = 27 * 27;       // 729
constexpr int ROWS  = NB * 14 * 14;  // 12544

#define RMS_EPS 1e-6f
#define GAMMA_LOG2 (-0.00144344319f)   // log2(0.999)

__device__ __forceinline__ void  stf(float* p, float v) { *p = v; }
__device__ __forceinline__ void  stf(bf16* p, float v)  { *p = __float2bfloat16(v); }

__device__ __forceinline__ void gload_lds16(const bf16* g, bf16* l) {
    __builtin_amdgcn_global_load_lds(
        (const __attribute__((address_space(1))) void*)g,
        (__attribute__((address_space(3))) void*)l, 16, 0, 0);
}

#define VMCNT(n) asm volatile("s_waitcnt vmcnt(" #n ")" ::: "memory")
#define BAR() do { __builtin_amdgcn_sched_barrier(0); __builtin_amdgcn_s_barrier(); \
                   __builtin_amdgcn_sched_barrier(0); } while (0)

// ---------------------------------------------------------------------------
__global__ void k_rpe_pos(const float* __restrict__ w, const float* __restrict__ bias,
                          float* __restrict__ out) {
    int p = blockIdx.x;
    float ii = (float)(p / 27 - 13);
    float jj = (float)(p % 27 - 13);
    for (int c = threadIdx.x; c < 512; c += 256)
        out[p * 512 + c] = ii * w[c] + jj * w[512 + c] + bias[c];
}

// ---------------------------------------------------------------------------
template <typename TO>
__global__ void k_rmsnorm_relu(const float* __restrict__ in, TO* __restrict__ out) {
    int r = blockIdx.x;
    const float* x = in + (size_t)r * 512;
    float v0 = x[threadIdx.x];
    float v1 = x[threadIdx.x + 256];
    float s = v0 * v0 + v1 * v1;
    #pragma unroll
    for (int off = 32; off; off >>= 1) s += __shfl_down(s, off, 64);
    __shared__ float ps[4];
    if ((threadIdx.x & 63) == 0) ps[threadIdx.x >> 6] = s;
    __syncthreads();
    float tot = ps[0] + ps[1] + ps[2] + ps[3];
    float scale = rsqrtf(tot * (1.0f / 512.0f) + RMS_EPS);
    stf(&out[(size_t)r * 512 + threadIdx.x],       fmaxf(v0 * scale, 0.0f));
    stf(&out[(size_t)r * 512 + threadIdx.x + 256], fmaxf(v1 * scale, 0.0f));
}

// ---------------------------------------------------------------------------
// Small-tile MFMA GEMM for the RPE chain: 64x64 tile, BK=32, 4 waves.
template <int EPI, typename TO>
__global__ __launch_bounds__(256) void k_mgemm_s(const bf16* __restrict__ A,
                                                 const bf16* __restrict__ Bt,
                                                 const float* __restrict__ bias,
                                                 TO* __restrict__ out,
                                                 int M, int N, int K) {
    __shared__ bf16 As[64 * 32];
    __shared__ bf16 Bs[64 * 32];
    const int tid = threadIdx.x;
    const int m0 = blockIdx.y * 64;
    const int n0 = blockIdx.x * 64;
    const int lane = tid & 63;
    const int w = tid >> 6;
    const int lr = lane & 15;
    const int lk = (lane >> 4) * 8;

    f32x4 acc[4] = {};
    const int row = tid >> 2;
    const int seg = (tid & 3) * 8;

    for (int k0 = 0; k0 < K; k0 += 32) {
        gload_lds16(&A[(size_t)(m0 + row) * K + k0 + seg], &As[tid * 8]);
        gload_lds16(&Bt[(size_t)(n0 + row) * K + k0 + seg], &Bs[tid * 8]);
        __syncthreads();
        bf16x8 af = *(const bf16x8*)&As[(w * 16 + lr) * 32 + lk];
        #pragma unroll
        for (int j = 0; j < 4; ++j) {
            bf16x8 bf = *(const bf16x8*)&Bs[(j * 16 + lr) * 32 + lk];
            acc[j] = __builtin_amdgcn_mfma_f32_16x16x32_bf16(af, bf, acc[j], 0, 0, 0);
        }
        __syncthreads();
    }

    const int crow = (lane >> 4) * 4;
    const int ccol = lane & 15;
    #pragma unroll
    for (int j = 0; j < 4; ++j) {
        int gc = n0 + j * 16 + ccol;
        float bb = bias[gc];
        #pragma unroll
        for (int r = 0; r < 4; ++r) {
            int gr = m0 + w * 16 + crow + r;
            if (gr < M) {
                float val = acc[j][r] + bb;
                if (EPI == 2) {
                    int i = gr / 27, jj = gr % 27;
                    val *= exp2f((float)(abs(i - 13) + abs(jj - 13)) * GAMMA_LOG2);
                }
                stf(&out[(size_t)gr * N + gc], val);
            }
        }
    }
}

// ---------------------------------------------------------------------------
// 8-phase 256x256 MFMA GEMM (m201-style template, plain HIP).
// BM=BN=256, BK=64, 512 threads = 8 waves (2M x 4N), per-wave out 128x64.
// LDS 128 KiB: A/B x dbuf x [khalf][256 rows][32 cols bf16], XOR-swizzled
// via pre-swizzled global source + swizzled ds_read (involution, rule 21).
// Counted vmcnt keeps 6 stage-units (12 loads) in flight; never drains to 0
// mid-loop. Requires M%256==0, N%256==0, K==KT*64.
template <int KT, int EPI, typename TO>
__global__ __launch_bounds__(512, 2) void k_mgemm8(const bf16* __restrict__ A, int lda,
                                                   const bf16* __restrict__ Bt,
                                                   const float* __restrict__ bias,
                                                   TO* __restrict__ out, int ldo,
                                                   int nb /* N/256 */) {
    constexpr int K = KT * 64;
    __shared__ __align__(16) char lds[131072];

    const int tid = threadIdx.x;
    const int lane = tid & 63;
    const int wid = tid >> 6;
    const int wr = wid >> 2;          // 0..1
    const int wc = wid & 3;           // 0..3

    int wgid = blockIdx.x;
    if ((gridDim.x & 7) == 0) {       // XCD swizzle (bijective when %8==0)
        int cpx = gridDim.x >> 3;
        wgid = (wgid & 7) * cpx + (wgid >> 3);
    }
    const int m0 = (wgid / nb) * 256;
    const int n0 = (wgid % nb) * 256;

    // LDS region: A buf d -> d*32768 ; B buf d -> 65536 + d*32768 ;
    // within: khalf*16384 + row*64 + colbyte (32 bf16 cols per khalf)
    auto ldsA = [&](int d, int kh) -> char* { return (char*)lds + d * 32768 + kh * 16384; };
    auto ldsB = [&](int d, int kh) -> char* { return (char*)lds + 65536 + d * 32768 + kh * 16384; };

    // stage one unit (16 KB = 256 rows x 32 cols) : 2 global_load_lds / thread
    auto stage = [&](int op, int kh, int t) {
        char* base = op ? ldsB(t & 1, kh) : ldsA(t & 1, kh);
        const bf16* g = op ? Bt : A;
        const int rowbase = op ? n0 : m0;
        const int ld = op ? K : lda;
        #pragma unroll
        for (int l = 0; l < 2; ++l) {
            int q = tid + l * 512;            // chunk 0..1023
            int r = q >> 2;                   // row 0..255
            int cb = (q & 3) * 16;            // 16B chunk within 64B row
            int cbl = cb ^ ((r & 3) << 4);    // logical col (inverse swizzle)
            const bf16* src = g + (size_t)(rowbase + r) * ld + t * 64 + kh * 32 + (cbl >> 1);
            gload_lds16(src, (bf16*)(base + q * 16));
        }
    };
    auto rdA = [&](int d, int ks, int mi) -> bf16x8 {
        int row = wr * 128 + mi * 16 + (lane & 15);
        int cb = ((lane >> 4) * 16) ^ ((row & 3) << 4);
        return *(const bf16x8*)(ldsA(d, ks) + row * 64 + cb);
    };
    auto rdB = [&](int d, int ks, int nj) -> bf16x8 {
        int row = wc * 64 + nj * 16 + (lane & 15);
        int cb = ((lane >> 4) * 16) ^ ((row & 3) << 4);
        return *(const bf16x8*)(ldsB(d, ks) + row * 64 + cb);
    };

    f32x4 acc[8][4] = {};
    bf16x8 aF[8], bF[4];

    // Prologue: 7 units (tile0 all 4, tile1 A0,B0,A1). B1(1) staged at (0,P0).
    stage(0, 0, 0); stage(1, 0, 0); stage(0, 1, 0); stage(1, 1, 0);
    stage(0, 0, 1); stage(1, 0, 1); stage(0, 1, 1);

    #pragma unroll
    for (int t = 0; t < KT; ++t) {
        const int d = t & 1;
        // ---- P0: needs A-Kh0(t), B-Kh0(t) ----
        if (t + 1 < KT) stage(1, 1, t + 1);          // B-Kh1(t+1) -> buf d^1
        if (t + 1 < KT) { VMCNT(12); } else { VMCNT(4); }
        BAR();
        #pragma unroll
        for (int mi = 0; mi < 8; ++mi) aF[mi] = rdA(d, 0, mi);
        #pragma unroll
        for (int nj = 0; nj < 4; ++nj) bF[nj] = rdB(d, 0, nj);
        __builtin_amdgcn_s_setprio(1);
        #pragma unroll
        for (int mi = 0; mi < 4; ++mi)
            #pragma unroll
            for (int nj = 0; nj < 4; ++nj)
                acc[mi][nj] = __builtin_amdgcn_mfma_f32_16x16x32_bf16(aF[mi], bF[nj], acc[mi][nj], 0, 0, 0);
        __builtin_amdgcn_s_setprio(0);
        BAR();
        // ---- P1 ----
        if (t + 2 < KT) stage(0, 0, t + 2);          // A-Kh0(t+2) over A-Kh0(t) [dead]
        __builtin_amdgcn_s_setprio(1);
        #pragma unroll
        for (int mi = 4; mi < 8; ++mi)
            #pragma unroll
            for (int nj = 0; nj < 4; ++nj)
                acc[mi][nj] = __builtin_amdgcn_mfma_f32_16x16x32_bf16(aF[mi], bF[nj], acc[mi][nj], 0, 0, 0);
        __builtin_amdgcn_s_setprio(0);
        BAR();
        // ---- P2: needs A-Kh1(t), B-Kh1(t) ----
        if (t + 2 < KT) stage(1, 0, t + 2);          // B-Kh0(t+2) over B-Kh0(t) [dead]
        if (t + 2 < KT)      { VMCNT(12); }
        else if (t + 1 < KT) { VMCNT(8); }
        else                 { VMCNT(0); }
        BAR();
        #pragma unroll
        for (int mi = 0; mi < 8; ++mi) aF[mi] = rdA(d, 1, mi);
        #pragma unroll
        for (int nj = 0; nj < 4; ++nj) bF[nj] = rdB(d, 1, nj);
        __builtin_amdgcn_s_setprio(1);
        #pragma unroll
        for (int mi = 0; mi < 4; ++mi)
            #pragma unroll
            for (int nj = 0; nj < 4; ++nj)
                acc[mi][nj] = __builtin_amdgcn_mfma_f32_16x16x32_bf16(aF[mi], bF[nj], acc[mi][nj], 0, 0, 0);
        __builtin_amdgcn_s_setprio(0);
        BAR();
        // ---- P3 ----
        if (t + 2 < KT) stage(0, 1, t + 2);          // A-Kh1(t+2) over A-Kh1(t) [dead]
        __builtin_amdgcn_s_setprio(1);
        #pragma unroll
        for (int mi = 4; mi < 8; ++mi)
            #pragma unroll
            for (int nj = 0; nj < 4; ++nj)
                acc[mi][nj] = __builtin_amdgcn_mfma_f32_16x16x32_bf16(aF[mi], bF[nj], acc[mi][nj], 0, 0, 0);
        __builtin_amdgcn_s_setprio(0);
        BAR();
    }

    // Epilogue: C/D layout col=lane&15, row=(lane>>4)*4+r
    const int crow = (lane >> 4) * 4;
    const int ccol = lane & 15;
    #pragma unroll
    for (int mi = 0; mi < 8; ++mi)
        #pragma unroll
        for (int nj = 0; nj < 4; ++nj) {
            int gc = n0 + wc * 64 + nj * 16 + ccol;
            float bb = bias[gc];
            #pragma unroll
            for (int r = 0; r < 4; ++r) {
                int gr = m0 + wr * 128 + mi * 16 + crow + r;
                float val = acc[mi][nj][r] + bb;
                if (EPI == 1) val = val / (1.0f + expf(-val));
                stf(&out[(size_t)gr * ldo + gc], val);
            }
        }
}

// ---------------------------------------------------------------------------
// fp32 [R][C] -> bf16 [C][R] transpose (weights prep)
__global__ __launch_bounds__(256) void k_transpose(const float* __restrict__ src,
                                                   bf16* __restrict__ dst, int R, int C) {
    __shared__ float t[32][33];
    int bx = blockIdx.x * 32;
    int by = blockIdx.y * 32;
    int tx = threadIdx.x & 31, ty = threadIdx.x >> 5;
    #pragma unroll
    for (int i = 0; i < 4; ++i)
        t[ty + i * 8][tx] = src[(size_t)(by + ty + i * 8) * C + bx + tx];
    __syncthreads();
    #pragma unroll
    for (int i = 0; i < 4; ++i)
        dst[(size_t)(bx + ty + i * 8) * R + by + tx] = __float2bfloat16(t[tx][ty + i * 8]);
}

// ---------------------------------------------------------------------------
__global__ void k_cvt_bf16(const float* __restrict__ src, bf16* __restrict__ dst, int n4) {
    int i = blockIdx.x * blockDim.x + threadIdx.x;
    if (i < n4) {
        float4 v = *(const float4*)&src[i * 4];
        bf16* d = &dst[i * 4];
        d[0] = __float2bfloat16(v.x);
        d[1] = __float2bfloat16(v.y);
        d[2] = __float2bfloat16(v.z);
        d[3] = __float2bfloat16(v.w);
    }
}

__global__ void k_bias_uv(const float* __restrict__ bu, const float* __restrict__ bv,
                          float* __restrict__ dst) {
    int c = blockIdx.x * 256 + threadIdx.x;
    if (c < 2048) dst[c] = (c < 1024) ? bu[c] : bv[c - 1024];
}

// ---------------------------------------------------------------------------
// v channel transpose: Vt[c][b][ij(pad 224)] = v[b*196+ij][c]
__global__ __launch_bounds__(256) void k_vt(const bf16* __restrict__ uv,
                                            bf16* __restrict__ Vt) {
    const int c0 = blockIdx.x * 64;
    const int b  = blockIdx.y;
    const int tid = threadIdx.x;
    __shared__ bf16 t[196][66];
    for (int f = tid; f < 196 * 64; f += 256) {
        int ij = f >> 6, cl = f & 63;
        t[ij][cl] = uv[((size_t)b * 196 + ij) * 2048 + 1024 + c0 + cl];
    }
    __syncthreads();
    const bf16 z = __float2bfloat16(0.0f);
    for (int f = tid; f < 64 * 224; f += 256) {
        int cl = f / 224, ij = f - cl * 224;
        Vt[((size_t)(c0 + cl) * 64 + b) * 224 + ij] = (ij < 196) ? t[ij][cl] : z;
    }
}

// ---------------------------------------------------------------------------
// Per-channel Toeplitz GEMM: Yt[cl][pq][b] = sum_ij T_c[pq][ij] * Vt[c][b][ij]
__global__ __launch_bounds__(256) void k_convm(const bf16* __restrict__ Ab,
                                               const bf16* __restrict__ Vt,
                                               bf16* __restrict__ Yt, int cbase) {
    __shared__ __align__(16) bf16 Ts[112 * 232];
    __shared__ bf16 As[736];
    const int mh = blockIdx.x;
    const int cl = blockIdx.y;
    const int c = cbase + cl;
    const int tid = threadIdx.x;
    const int mbase = mh * 112;

    for (int e = tid; e < 729; e += 256)
        As[e] = Ab[(size_t)e * 1024 + c];
    __syncthreads();

    const bf16 z = __float2bfloat16(0.0f);
    if (tid < 224) {
        const int i = tid / 14, j = tid - i * 14;
        const bool kvalid = tid < 196;
        int p = mbase / 14, q = 0;
        for (int r = 0; r < 112; ++r) {
            bf16 val = z;
            if (kvalid && (mbase + r) < 196)
                val = As[(p - i + 13) * 27 + (q - j + 13)];
            Ts[r * 232 + tid] = val;
            if (++q == 14) { q = 0; ++p; }
        }
    }
    __syncthreads();

    const int lane = tid & 63;
    const int w = tid >> 6;
    const int lr = lane & 15;
    const int lk = (lane >> 4) * 8;
    const bf16* Vc = Vt + (size_t)c * 64 * 224;

    bf16x8 bfr[7];
    #pragma unroll
    for (int ks = 0; ks < 7; ++ks)
        bfr[ks] = *(const bf16x8*)&Vc[(size_t)(w * 16 + lr) * 224 + ks * 32 + lk];

    f32x4 acc[7] = {};
    #pragma unroll
    for (int ks = 0; ks < 7; ++ks)
        #pragma unroll
        for (int mi = 0; mi < 7; ++mi) {
            bf16x8 a = *(const bf16x8*)&Ts[(mi * 16 + lr) * 232 + ks * 32 + lk];
            acc[mi] = __builtin_amdgcn_mfma_f32_16x16x32_bf16(a, bfr[ks], acc[mi], 0, 0, 0);
        }

    const int crow = (lane >> 4) * 4;
    const int bb = w * 16 + (lane & 15);
    #pragma unroll
    for (int mi = 0; mi < 7; ++mi) {
        int pq = mbase + mi * 16 + crow;
        #pragma unroll
        for (int r = 0; r < 4; ++r)
            if (pq + r < 196)
                Yt[((size_t)cl * 196 + pq + r) * 64 + bb] = __float2bfloat16(acc[mi][r]);
    }
}

// ---------------------------------------------------------------------------
__global__ __launch_bounds__(256) void k_gate(bf16* __restrict__ uv,
                                              const bf16* __restrict__ Yt, int cbase) {
    const int pq = blockIdx.x;
    const int ct = blockIdx.y;
    const int tid = threadIdx.x;
    __shared__ float t[64][65];
    for (int f = tid; f < 64 * 64; f += 256) {
        int cr = f >> 6, bcol = f & 63;
        t[cr][bcol] = __bfloat162float(Yt[((size_t)(ct * 64 + cr) * 196 + pq) * 64 + bcol]);
    }
    __syncthreads();
    for (int f = tid; f < 64 * 64; f += 256) {
        int br = f >> 6, cc = f & 63;
        size_t row = (size_t)br * 196 + pq;
        int cglob = cbase + ct * 64 + cc;
        float uu = __bfloat162float(uv[row * 2048 + cglob]);
        uv[row * 2048 + 1024 + cglob] = __float2bfloat16(t[cc][br] * uu);
    }
}

// ---------------------------------------------------------------------------
extern "C" void kernel_launch(void* const* d_in, const int* in_sizes, int n_in,
                              void* d_out, int out_size, void* d_ws, size_t ws_size,
                              hipStream_t stream) {
    const float* x    = (const float*)d_in[0];
    const float* Wu   = (const float*)d_in[3];
    const float* bu   = (const float*)d_in[4];
    const float* Wv   = (const float*)d_in[5];
    const float* bv   = (const float*)d_in[6];
    const float* Wo   = (const float*)d_in[7];
    const float* bo   = (const float*)d_in[8];
    const float* rpw  = (const float*)d_in[9];
    const float* rpb  = (const float*)d_in[10];
    const float* w1   = (const float*)d_in[11];
    const float* b1   = (const float*)d_in[12];
    const float* w2   = (const float*)d_in[13];
    const float* b2   = (const float*)d_in[14];
    const float* w3   = (const float*)d_in[15];
    const float* b3   = (const float*)d_in[16];
    const float* wOut = (const float*)d_in[17];
    const float* bOut = (const float*)d_in[18];

    char* ws = (char*)d_ws;
    size_t off = 0;
    auto take = [&](size_t bytes) { char* p = ws + off; off += (bytes + 255) & ~size_t(255); return p; };
    float* rA     = (float*)take((size_t)RPOS * 512 * 4);
    float* rB     = (float*)take((size_t)RPOS * 512 * 4);
    bf16*  rn     = (bf16*)take((size_t)RPOS * 512 * 2 + 40960);
    bf16*  Ab     = (bf16*)take((size_t)RPOS * 1024 * 2);
    bf16*  xb     = (bf16*)take((size_t)ROWS * EE * 2);           // reused as Yt
    bf16*  WuvT   = (bf16*)take((size_t)2048 * 512 * 2);
    bf16*  WoT    = (bf16*)take((size_t)512 * 1024 * 2);
    bf16*  w1T    = (bf16*)take((size_t)512 * 512 * 2);
    bf16*  w2T    = (bf16*)take((size_t)512 * 512 * 2);
    bf16*  w3T    = (bf16*)take((size_t)512 * 512 * 2);
    bf16*  wOutT  = (bf16*)take((size_t)1024 * 512 * 2);
    float* biasUv = (float*)take(2048 * 4);
    bf16*  uvb    = (bf16*)take((size_t)ROWS * 2048 * 2);
    bf16*  Vt     = (bf16*)take((size_t)1024 * 64 * 224 * 2);
    bf16*  Yt     = (bf16*)xb;

    // --- weight prep ---
    k_transpose<<<dim3(32, 16), 256, 0, stream>>>(Wu, WuvT, 512, 1024);
    k_transpose<<<dim3(32, 16), 256, 0, stream>>>(Wv, WuvT + (size_t)1024 * 512, 512, 1024);
    k_transpose<<<dim3(16, 32), 256, 0, stream>>>(Wo, WoT, 1024, 512);
    k_transpose<<<dim3(16, 16), 256, 0, stream>>>(w1, w1T, 512, 512);
    k_transpose<<<dim3(16, 16), 256, 0, stream>>>(w2, w2T, 512, 512);
    k_transpose<<<dim3(16, 16), 256, 0, stream>>>(w3, w3T, 512, 512);
    k_transpose<<<dim3(32, 16), 256, 0, stream>>>(wOut, wOutT, 512, 1024);
    k_bias_uv<<<8, 256, 0, stream>>>(bu, bv, biasUv);
    k_cvt_bf16<<<(ROWS * EE / 4 + 255) / 256, 256, 0, stream>>>(x, xb, ROWS * EE / 4);

    // --- RPE MLP (MFMA small tiles) ---
    k_rpe_pos<<<RPOS, 256, 0, stream>>>(rpw, rpb, rA);
    k_rmsnorm_relu<bf16><<<RPOS, 256, 0, stream>>>(rA, rn);
    k_mgemm_s<0, float><<<dim3(8, 12), 256, 0, stream>>>(rn, w1T, b1, rB, RPOS, 512, 512);
    k_rmsnorm_relu<bf16><<<RPOS, 256, 0, stream>>>(rB, rn);
    k_mgemm_s<0, float><<<dim3(8, 12), 256, 0, stream>>>(rn, w2T, b2, rA, RPOS, 512, 512);
    k_rmsnorm_relu<bf16><<<RPOS, 256, 0, stream>>>(rA, rn);
    k_mgemm_s<0, float><<<dim3(8, 12), 256, 0, stream>>>(rn, w3T, b3, rB, RPOS, 512, 512);
    k_rmsnorm_relu<bf16><<<RPOS, 256, 0, stream>>>(rB, rn);
    k_mgemm_s<2, bf16><<<dim3(16, 12), 256, 0, stream>>>(rn, wOutT, bOut, Ab, RPOS, 1024, 512);

    // --- uv = silu(x @ [Wu|Wv] + [bu|bv])  (8-phase 256^2, KT=8) ---
    k_mgemm8<8, 1, bf16><<<392, 512, 0, stream>>>(xb, 512, WuvT, biasUv, uvb, 2048, 8);

    // --- v -> channel-major Vt ---
    k_vt<<<dim3(16, 64), 256, 0, stream>>>(uvb, Vt);

    // --- Toeplitz conv (MFMA) + gating ---
    for (int h = 0; h < 2; ++h) {
        k_convm<<<dim3(2, 512), 256, 0, stream>>>(Ab, Vt, Yt, h * 512);
        k_gate<<<dim3(196, 8), 256, 0, stream>>>(uvb, Yt, h * 512);
    }

    // --- out = g @ Wo + bo  (8-phase 256^2, KT=16) ---
    k_mgemm8<16, 0, float><<<98, 512, 0, stream>>>(uvb + 1024, 2048, WoT, bo,
                                                   (float*)d_out, 512, 2);
}

// Round 8
// 253.825 us; speedup vs baseline: 1.0224x; 1.0224x over previous
//
#include <hip/hip_runtime.h>
#include <hip/hip_bf16.h>

typedef __hip_bfloat16 bf16;
typedef __attribute__((ext_vector_type(8))) short bf16x8;
typedef __attribute__((ext_vector_type(4))) float f32x4;

// Problem constants: B=64, n=m=14, E=512, D1=1024, heads=8
constexpr int NB    = 64;
constexpr int EE    = 512;
constexpr int DD1   = 1024;
constexpr int RPOS  = 27 * 27;       // 729
constexpr int ROWS  = NB * 14 * 14;  // 12544

#define RMS_EPS 1e-6f
#define GAMMA_LOG2 (-0.00144344319f)   // log2(0.999)

__device__ __forceinline__ void  stf(float* p, float v) { *p = v; }
__device__ __forceinline__ void  stf(bf16* p, float v)  { *p = __float2bfloat16(v); }

__device__ __forceinline__ void gload_lds16(const bf16* g, bf16* l) {
    __builtin_amdgcn_global_load_lds(
        (const __attribute__((address_space(1))) void*)g,
        (__attribute__((address_space(3))) void*)l, 16, 0, 0);
}

#define VMCNT(n) asm volatile("s_waitcnt vmcnt(" #n ")" ::: "memory")

// ---------------------------------------------------------------------------
// fused: r0 = ii*w0 + jj*w1 + b;  rn = bf16(relu(rms_norm(r0)))
__global__ void k_rpe_pos_norm(const float* __restrict__ w, const float* __restrict__ bias,
                               bf16* __restrict__ out) {
    int p = blockIdx.x;
    float ii = (float)(p / 27 - 13);
    float jj = (float)(p % 27 - 13);
    int c0 = threadIdx.x, c1 = threadIdx.x + 256;
    float v0 = ii * w[c0] + jj * w[512 + c0] + bias[c0];
    float v1 = ii * w[c1] + jj * w[512 + c1] + bias[c1];
    float s = v0 * v0 + v1 * v1;
    #pragma unroll
    for (int off = 32; off; off >>= 1) s += __shfl_down(s, off, 64);
    __shared__ float ps[4];
    if ((threadIdx.x & 63) == 0) ps[threadIdx.x >> 6] = s;
    __syncthreads();
    float tot = ps[0] + ps[1] + ps[2] + ps[3];
    float scale = rsqrtf(tot * (1.0f / 512.0f) + RMS_EPS);
    out[(size_t)p * 512 + c0] = __float2bfloat16(fmaxf(v0 * scale, 0.0f));
    out[(size_t)p * 512 + c1] = __float2bfloat16(fmaxf(v1 * scale, 0.0f));
}

// ---------------------------------------------------------------------------
template <typename TO>
__global__ void k_rmsnorm_relu(const float* __restrict__ in, TO* __restrict__ out) {
    int r = blockIdx.x;
    const float* x = in + (size_t)r * 512;
    float v0 = x[threadIdx.x];
    float v1 = x[threadIdx.x + 256];
    float s = v0 * v0 + v1 * v1;
    #pragma unroll
    for (int off = 32; off; off >>= 1) s += __shfl_down(s, off, 64);
    __shared__ float ps[4];
    if ((threadIdx.x & 63) == 0) ps[threadIdx.x >> 6] = s;
    __syncthreads();
    float tot = ps[0] + ps[1] + ps[2] + ps[3];
    float scale = rsqrtf(tot * (1.0f / 512.0f) + RMS_EPS);
    stf(&out[(size_t)r * 512 + threadIdx.x],       fmaxf(v0 * scale, 0.0f));
    stf(&out[(size_t)r * 512 + threadIdx.x + 256], fmaxf(v1 * scale, 0.0f));
}

// ---------------------------------------------------------------------------
// Small-tile MFMA GEMM for the RPE chain: 64x64 tile, BK=32, 4 waves.
template <int EPI, typename TO>
__global__ __launch_bounds__(256) void k_mgemm_s(const bf16* __restrict__ A,
                                                 const bf16* __restrict__ Bt,
                                                 const float* __restrict__ bias,
                                                 TO* __restrict__ out,
                                                 int M, int N, int K) {
    __shared__ bf16 As[64 * 32];
    __shared__ bf16 Bs[64 * 32];
    const int tid = threadIdx.x;
    const int m0 = blockIdx.y * 64;
    const int n0 = blockIdx.x * 64;
    const int lane = tid & 63;
    const int w = tid >> 6;
    const int lr = lane & 15;
    const int lk = (lane >> 4) * 8;

    f32x4 acc[4] = {};
    const int row = tid >> 2;
    const int seg = (tid & 3) * 8;

    for (int k0 = 0; k0 < K; k0 += 32) {
        gload_lds16(&A[(size_t)(m0 + row) * K + k0 + seg], &As[tid * 8]);
        gload_lds16(&Bt[(size_t)(n0 + row) * K + k0 + seg], &Bs[tid * 8]);
        __syncthreads();
        bf16x8 af = *(const bf16x8*)&As[(w * 16 + lr) * 32 + lk];
        #pragma unroll
        for (int j = 0; j < 4; ++j) {
            bf16x8 bf = *(const bf16x8*)&Bs[(j * 16 + lr) * 32 + lk];
            acc[j] = __builtin_amdgcn_mfma_f32_16x16x32_bf16(af, bf, acc[j], 0, 0, 0);
        }
        __syncthreads();
    }

    const int crow = (lane >> 4) * 4;
    const int ccol = lane & 15;
    #pragma unroll
    for (int j = 0; j < 4; ++j) {
        int gc = n0 + j * 16 + ccol;
        float bb = bias[gc];
        #pragma unroll
        for (int r = 0; r < 4; ++r) {
            int gr = m0 + w * 16 + crow + r;
            if (gr < M) {
                float val = acc[j][r] + bb;
                if (EPI == 2) {
                    int i = gr / 27, jj = gr % 27;
                    val *= exp2f((float)(abs(i - 13) + abs(jj - 13)) * GAMMA_LOG2);
                }
                stf(&out[(size_t)gr * N + gc], val);
            }
        }
    }
}

// ---------------------------------------------------------------------------
// 8-phase 256x256 MFMA GEMM, template-ordered (m201 discipline).
// BM=BN=256, BK=64, 512 thr = 8 waves (2M x 4N), per-wave 128x64 out.
// Staging unit = [256 rows x 32 K-cols] (16 KB, 2 gload_lds/thread).
// Per phase: {ds_reads || stage 1 unit -> [vmcnt] -> s_barrier (sched pin only
// after the two guarantee-waits per tile) -> setprio 16xMFMA -> s_barrier}.
// Uniform vmcnt(8) = 4 units in flight; epilogue drains 8->4->0.
// LDS swizzle: chunk ^= (row ^ row>>2)&3 => 2-way ds_read conflict (free).
// Requires M%256==0, N%256==0, K==KT*64.
template <int KT, int EPI, typename TO>
__global__ __launch_bounds__(512, 2) void k_mgemm8(const bf16* __restrict__ A, int lda,
                                                   const bf16* __restrict__ Bt,
                                                   const float* __restrict__ bias,
                                                   TO* __restrict__ out, int ldo,
                                                   int nb /* N/256 */) {
    constexpr int K = KT * 64;
    __shared__ __align__(16) char lds[131072];

    const int tid = threadIdx.x;
    const int lane = tid & 63;
    const int wid = tid >> 6;
    const int wr = wid >> 2;          // 0..1
    const int wc = wid & 3;           // 0..3

    int wgid = blockIdx.x;
    if ((gridDim.x & 7) == 0) {       // XCD swizzle (bijective when %8==0)
        int cpx = gridDim.x >> 3;
        wgid = (wgid & 7) * cpx + (wgid >> 3);
    }
    const int m0 = (wgid / nb) * 256;
    const int n0 = (wgid % nb) * 256;

    auto ldsA = [&](int d, int kh) -> char* { return (char*)lds + d * 32768 + kh * 16384; };
    auto ldsB = [&](int d, int kh) -> char* { return (char*)lds + 65536 + d * 32768 + kh * 16384; };

    // stage one unit (256 rows x 32 K-cols): linear LDS dest, inverse-swizzled src
    auto stage = [&](int op, int kh, int tt) {
        char* base = op ? ldsB(tt & 1, kh) : ldsA(tt & 1, kh);
        const bf16* g = op ? Bt : A;
        const int rowbase = op ? n0 : m0;
        const int ldr = op ? K : lda;
        #pragma unroll
        for (int l = 0; l < 2; ++l) {
            int q = tid + l * 512;                    // chunk 0..1023
            int r = q >> 2;                           // row 0..255
            int cl = (q & 3) ^ ((r ^ (r >> 2)) & 3);  // logical 8-elem chunk
            const bf16* src = g + (size_t)(rowbase + r) * ldr + tt * 64 + kh * 32 + cl * 8;
            gload_lds16(src, (bf16*)(base + q * 16));
        }
    };
    // reads (swizzled, same involution)
    auto rdA = [&](int d, int ks, int mi) -> bf16x8 {
        int row = wr * 128 + mi * 16 + (lane & 15);
        int ch = (lane >> 4) ^ ((row ^ (row >> 2)) & 3);
        return *(const bf16x8*)(ldsA(d, ks) + row * 64 + ch * 16);
    };
    auto rdB = [&](int d, int ks, int nj) -> bf16x8 {
        int row = wc * 64 + nj * 16 + (lane & 15);
        int ch = (lane >> 4) ^ ((row ^ (row >> 2)) & 3);
        return *(const bf16x8*)(ldsB(d, ks) + row * 64 + ch * 16);
    };

    f32x4 acc[8][4] = {};
    bf16x8 aF[4], bF[4];

    // Prologue: A0(0) B0(0) A1(0) B1(0) A0(1) B0(1); wait tile0 fully landed.
    stage(0, 0, 0); stage(1, 0, 0); stage(0, 1, 0); stage(1, 1, 0);
    stage(0, 0, 1); stage(1, 0, 1);
    VMCNT(8);
    __builtin_amdgcn_s_barrier();
    __builtin_amdgcn_sched_barrier(0);

    #pragma unroll
    for (int t = 0; t < KT; ++t) {
        const int d = t & 1;
        // ---- Ph0: mi0-3 x ks0 ----
        #pragma unroll
        for (int mi = 0; mi < 4; ++mi) aF[mi] = rdA(d, 0, mi);
        #pragma unroll
        for (int nj = 0; nj < 4; ++nj) bF[nj] = rdB(d, 0, nj);
        if (t + 1 < KT) stage(0, 1, t + 1);          // A-Kh1(t+1)
        __builtin_amdgcn_s_barrier();
        __builtin_amdgcn_s_setprio(1);
        #pragma unroll
        for (int mi = 0; mi < 4; ++mi)
            #pragma unroll
            for (int nj = 0; nj < 4; ++nj)
                acc[mi][nj] = __builtin_amdgcn_mfma_f32_16x16x32_bf16(aF[mi], bF[nj], acc[mi][nj], 0, 0, 0);
        __builtin_amdgcn_s_setprio(0);
        __builtin_amdgcn_s_barrier();
        // ---- Ph1: mi4-7 x ks0 ----
        #pragma unroll
        for (int mi = 0; mi < 4; ++mi) aF[mi] = rdA(d, 0, mi + 4);
        if (t + 1 < KT) stage(1, 1, t + 1);          // B-Kh1(t+1)
        if (t + 1 < KT) { VMCNT(8); } else { VMCNT(0); }   // W1: Kh1(t) landed
        __builtin_amdgcn_s_barrier();
        __builtin_amdgcn_sched_barrier(0);
        __builtin_amdgcn_s_setprio(1);
        #pragma unroll
        for (int mi = 0; mi < 4; ++mi)
            #pragma unroll
            for (int nj = 0; nj < 4; ++nj)
                acc[mi + 4][nj] = __builtin_amdgcn_mfma_f32_16x16x32_bf16(aF[mi], bF[nj], acc[mi + 4][nj], 0, 0, 0);
        __builtin_amdgcn_s_setprio(0);
        __builtin_amdgcn_s_barrier();
        // ---- Ph2: mi0-3 x ks1 ----
        #pragma unroll
        for (int mi = 0; mi < 4; ++mi) aF[mi] = rdA(d, 1, mi);
        #pragma unroll
        for (int nj = 0; nj < 4; ++nj) bF[nj] = rdB(d, 1, nj);
        if (t + 2 < KT) stage(0, 0, t + 2);          // A-Kh0(t+2)
        __builtin_amdgcn_s_barrier();
        __builtin_amdgcn_s_setprio(1);
        #pragma unroll
        for (int mi = 0; mi < 4; ++mi)
            #pragma unroll
            for (int nj = 0; nj < 4; ++nj)
                acc[mi][nj] = __builtin_amdgcn_mfma_f32_16x16x32_bf16(aF[mi], bF[nj], acc[mi][nj], 0, 0, 0);
        __builtin_amdgcn_s_setprio(0);
        __builtin_amdgcn_s_barrier();
        // ---- Ph3: mi4-7 x ks1 ----
        #pragma unroll
        for (int mi = 0; mi < 4; ++mi) aF[mi] = rdA(d, 1, mi + 4);
        if (t + 2 < KT) stage(1, 0, t + 2);          // B-Kh0(t+2)
        if (t + 2 < KT)      { VMCNT(8); }           // W2: Kh0(t+1) landed
        else if (t + 1 < KT) { VMCNT(4); }
        __builtin_amdgcn_s_barrier();
        __builtin_amdgcn_sched_barrier(0);
        __builtin_amdgcn_s_setprio(1);
        #pragma unroll
        for (int mi = 0; mi < 4; ++mi)
            #pragma unroll
            for (int nj = 0; nj < 4; ++nj)
                acc[mi + 4][nj] = __builtin_amdgcn_mfma_f32_16x16x32_bf16(aF[mi], bF[nj], acc[mi + 4][nj], 0, 0, 0);
        __builtin_amdgcn_s_setprio(0);
        __builtin_amdgcn_s_barrier();
    }

    // Epilogue: C/D layout col=lane&15, row=(lane>>4)*4+r
    const int crow = (lane >> 4) * 4;
    const int ccol = lane & 15;
    #pragma unroll
    for (int mi = 0; mi < 8; ++mi)
        #pragma unroll
        for (int nj = 0; nj < 4; ++nj) {
            int gc = n0 + wc * 64 + nj * 16 + ccol;
            float bb = bias[gc];
            #pragma unroll
            for (int r = 0; r < 4; ++r) {
                int gr = m0 + wr * 128 + mi * 16 + crow + r;
                float val = acc[mi][nj][r] + bb;
                if (EPI == 1) val = val / (1.0f + expf(-val));
                stf(&out[(size_t)gr * ldo + gc], val);
            }
        }
}

// ---------------------------------------------------------------------------
// fp32 [R][C] -> bf16 [C][R] transpose (weights prep)
__global__ __launch_bounds__(256) void k_transpose(const float* __restrict__ src,
                                                   bf16* __restrict__ dst, int R, int C) {
    __shared__ float t[32][33];
    int bx = blockIdx.x * 32;
    int by = blockIdx.y * 32;
    int tx = threadIdx.x & 31, ty = threadIdx.x >> 5;
    #pragma unroll
    for (int i = 0; i < 4; ++i)
        t[ty + i * 8][tx] = src[(size_t)(by + ty + i * 8) * C + bx + tx];
    __syncthreads();
    #pragma unroll
    for (int i = 0; i < 4; ++i)
        dst[(size_t)(bx + ty + i * 8) * R + by + tx] = __float2bfloat16(t[tx][ty + i * 8]);
}

// ---------------------------------------------------------------------------
__global__ void k_cvt_bf16(const float* __restrict__ src, bf16* __restrict__ dst, int n4) {
    int i = blockIdx.x * blockDim.x + threadIdx.x;
    if (i < n4) {
        float4 v = *(const float4*)&src[i * 4];
        bf16* d = &dst[i * 4];
        d[0] = __float2bfloat16(v.x);
        d[1] = __float2bfloat16(v.y);
        d[2] = __float2bfloat16(v.z);
        d[3] = __float2bfloat16(v.w);
    }
}

__global__ void k_bias_uv(const float* __restrict__ bu, const float* __restrict__ bv,
                          float* __restrict__ dst) {
    int c = blockIdx.x * 256 + threadIdx.x;
    if (c < 2048) dst[c] = (c < 1024) ? bu[c] : bv[c - 1024];
}

// ---------------------------------------------------------------------------
// v channel transpose: Vt[c][b][ij(pad 224)] = v[b*196+ij][c]
__global__ __launch_bounds__(256) void k_vt(const bf16* __restrict__ uv,
                                            bf16* __restrict__ Vt) {
    const int c0 = blockIdx.x * 64;
    const int b  = blockIdx.y;
    const int tid = threadIdx.x;
    __shared__ bf16 t[196][66];
    for (int f = tid; f < 196 * 64; f += 256) {
        int ij = f >> 6, cl = f & 63;
        t[ij][cl] = uv[((size_t)b * 196 + ij) * 2048 + 1024 + c0 + cl];
    }
    __syncthreads();
    const bf16 z = __float2bfloat16(0.0f);
    for (int f = tid; f < 64 * 224; f += 256) {
        int cl = f / 224, ij = f - cl * 224;
        Vt[((size_t)(c0 + cl) * 64 + b) * 224 + ij] = (ij < 196) ? t[ij][cl] : z;
    }
}

// ---------------------------------------------------------------------------
// Per-channel Toeplitz GEMM: Yt[cl][pq][b] = sum_ij T_c[pq][ij] * Vt[c][b][ij]
__global__ __launch_bounds__(256) void k_convm(const bf16* __restrict__ Ab,
                                               const bf16* __restrict__ Vt,
                                               bf16* __restrict__ Yt, int cbase) {
    __shared__ __align__(16) bf16 Ts[112 * 232];
    __shared__ bf16 As[736];
    const int mh = blockIdx.x;
    const int cl = blockIdx.y;
    const int c = cbase + cl;
    const int tid = threadIdx.x;
    const int mbase = mh * 112;

    for (int e = tid; e < 729; e += 256)
        As[e] = Ab[(size_t)e * 1024 + c];
    __syncthreads();

    const bf16 z = __float2bfloat16(0.0f);
    if (tid < 224) {
        const int i = tid / 14, j = tid - i * 14;
        const bool kvalid = tid < 196;
        int p = mbase / 14, q = 0;
        for (int r = 0; r < 112; ++r) {
            bf16 val = z;
            if (kvalid && (mbase + r) < 196)
                val = As[(p - i + 13) * 27 + (q - j + 13)];
            Ts[r * 232 + tid] = val;
            if (++q == 14) { q = 0; ++p; }
        }
    }
    __syncthreads();

    const int lane = tid & 63;
    const int w = tid >> 6;
    const int lr = lane & 15;
    const int lk = (lane >> 4) * 8;
    const bf16* Vc = Vt + (size_t)c * 64 * 224;

    bf16x8 bfr[7];
    #pragma unroll
    for (int ks = 0; ks < 7; ++ks)
        bfr[ks] = *(const bf16x8*)&Vc[(size_t)(w * 16 + lr) * 224 + ks * 32 + lk];

    f32x4 acc[7] = {};
    #pragma unroll
    for (int ks = 0; ks < 7; ++ks)
        #pragma unroll
        for (int mi = 0; mi < 7; ++mi) {
            bf16x8 a = *(const bf16x8*)&Ts[(mi * 16 + lr) * 232 + ks * 32 + lk];
            acc[mi] = __builtin_amdgcn_mfma_f32_16x16x32_bf16(a, bfr[ks], acc[mi], 0, 0, 0);
        }

    const int crow = (lane >> 4) * 4;
    const int bb = w * 16 + (lane & 15);
    #pragma unroll
    for (int mi = 0; mi < 7; ++mi) {
        int pq = mbase + mi * 16 + crow;
        #pragma unroll
        for (int r = 0; r < 4; ++r)
            if (pq + r < 196)
                Yt[((size_t)cl * 196 + pq + r) * 64 + bb] = __float2bfloat16(acc[mi][r]);
    }
}

// ---------------------------------------------------------------------------
__global__ __launch_bounds__(256) void k_gate(bf16* __restrict__ uv,
                                              const bf16* __restrict__ Yt, int cbase) {
    const int pq = blockIdx.x;
    const int ct = blockIdx.y;
    const int tid = threadIdx.x;
    __shared__ float t[64][65];
    for (int f = tid; f < 64 * 64; f += 256) {
        int cr = f >> 6, bcol = f & 63;
        t[cr][bcol] = __bfloat162float(Yt[((size_t)(ct * 64 + cr) * 196 + pq) * 64 + bcol]);
    }
    __syncthreads();
    for (int f = tid; f < 64 * 64; f += 256) {
        int br = f >> 6, cc = f & 63;
        size_t row = (size_t)br * 196 + pq;
        int cglob = cbase + ct * 64 + cc;
        float uu = __bfloat162float(uv[row * 2048 + cglob]);
        uv[row * 2048 + 1024 + cglob] = __float2bfloat16(t[cc][br] * uu);
    }
}

// ---------------------------------------------------------------------------
extern "C" void kernel_launch(void* const* d_in, const int* in_sizes, int n_in,
                              void* d_out, int out_size, void* d_ws, size_t ws_size,
                              hipStream_t stream) {
    const float* x    = (const float*)d_in[0];
    const float* Wu   = (const float*)d_in[3];
    const float* bu   = (const float*)d_in[4];
    const float* Wv   = (const float*)d_in[5];
    const float* bv   = (const float*)d_in[6];
    const float* Wo   = (const float*)d_in[7];
    const float* bo   = (const float*)d_in[8];
    const float* rpw  = (const float*)d_in[9];
    const float* rpb  = (const float*)d_in[10];
    const float* w1   = (const float*)d_in[11];
    const float* b1   = (const float*)d_in[12];
    const float* w2   = (const float*)d_in[13];
    const float* b2   = (const float*)d_in[14];
    const float* w3   = (const float*)d_in[15];
    const float* b3   = (const float*)d_in[16];
    const float* wOut = (const float*)d_in[17];
    const float* bOut = (const float*)d_in[18];

    char* ws = (char*)d_ws;
    size_t off = 0;
    auto take = [&](size_t bytes) { char* p = ws + off; off += (bytes + 255) & ~size_t(255); return p; };
    float* rA     = (float*)take((size_t)RPOS * 512 * 4);
    float* rB     = (float*)take((size_t)RPOS * 512 * 4);
    bf16*  rn     = (bf16*)take((size_t)RPOS * 512 * 2 + 40960);
    bf16*  Ab     = (bf16*)take((size_t)RPOS * 1024 * 2);
    bf16*  xb     = (bf16*)take((size_t)ROWS * EE * 2);           // reused as Yt
    bf16*  WuvT   = (bf16*)take((size_t)2048 * 512 * 2);
    bf16*  WoT    = (bf16*)take((size_t)512 * 1024 * 2);
    bf16*  w1T    = (bf16*)take((size_t)512 * 512 * 2);
    bf16*  w2T    = (bf16*)take((size_t)512 * 512 * 2);
    bf16*  w3T    = (bf16*)take((size_t)512 * 512 * 2);
    bf16*  wOutT  = (bf16*)take((size_t)1024 * 512 * 2);
    float* biasUv = (float*)take(2048 * 4);
    bf16*  uvb    = (bf16*)take((size_t)ROWS * 2048 * 2);
    bf16*  Vt     = (bf16*)take((size_t)1024 * 64 * 224 * 2);
    bf16*  Yt     = (bf16*)xb;

    // --- weight prep ---
    k_transpose<<<dim3(32, 16), 256, 0, stream>>>(Wu, WuvT, 512, 1024);
    k_transpose<<<dim3(32, 16), 256, 0, stream>>>(Wv, WuvT + (size_t)1024 * 512, 512, 1024);
    k_transpose<<<dim3(16, 32), 256, 0, stream>>>(Wo, WoT, 1024, 512);
    k_transpose<<<dim3(16, 16), 256, 0, stream>>>(w1, w1T, 512, 512);
    k_transpose<<<dim3(16, 16), 256, 0, stream>>>(w2, w2T, 512, 512);
    k_transpose<<<dim3(16, 16), 256, 0, stream>>>(w3, w3T, 512, 512);
    k_transpose<<<dim3(32, 16), 256, 0, stream>>>(wOut, wOutT, 512, 1024);
    k_bias_uv<<<8, 256, 0, stream>>>(bu, bv, biasUv);
    k_cvt_bf16<<<(ROWS * EE / 4 + 255) / 256, 256, 0, stream>>>(x, xb, ROWS * EE / 4);

    // --- RPE MLP (MFMA small tiles) ---
    k_rpe_pos_norm<<<RPOS, 256, 0, stream>>>(rpw, rpb, rn);
    k_mgemm_s<0, float><<<dim3(8, 12), 256, 0, stream>>>(rn, w1T, b1, rB, RPOS, 512, 512);
    k_rmsnorm_relu<bf16><<<RPOS, 256, 0, stream>>>(rB, rn);
    k_mgemm_s<0, float><<<dim3(8, 12), 256, 0, stream>>>(rn, w2T, b2, rA, RPOS, 512, 512);
    k_rmsnorm_relu<bf16><<<RPOS, 256, 0, stream>>>(rA, rn);
    k_mgemm_s<0, float><<<dim3(8, 12), 256, 0, stream>>>(rn, w3T, b3, rB, RPOS, 512, 512);
    k_rmsnorm_relu<bf16><<<RPOS, 256, 0, stream>>>(rB, rn);
    k_mgemm_s<2, bf16><<<dim3(16, 12), 256, 0, stream>>>(rn, wOutT, bOut, Ab, RPOS, 1024, 512);

    // --- uv = silu(x @ [Wu|Wv] + [bu|bv])  (8-phase 256^2, KT=8) ---
    k_mgemm8<8, 1, bf16><<<392, 512, 0, stream>>>(xb, 512, WuvT, biasUv, uvb, 2048, 8);

    // --- v -> channel-major Vt ---
    k_vt<<<dim3(16, 64), 256, 0, stream>>>(uvb, Vt);

    // --- Toeplitz conv (MFMA) + gating ---
    for (int h = 0; h < 2; ++h) {
        k_convm<<<dim3(2, 512), 256, 0, stream>>>(Ab, Vt, Yt, h * 512);
        k_gate<<<dim3(196, 8), 256, 0, stream>>>(uvb, Yt, h * 512);
    }

    // --- out = g @ Wo + bo  (8-phase 256^2, KT=16) ---
    k_mgemm8<16, 0, float><<<98, 512, 0, stream>>>(uvb + 1024, 2048, WoT, bo,
                                                   (float*)d_out, 512, 2);
}